// Round 1
// baseline (374.813 us; speedup 1.0000x reference)
//
#include <hip/hip_runtime.h>
#include <hip/hip_bf16.h>
#include <stdint.h>

#define TT   65536
#define NCH  16
#define CNOM 16
#define NBLK 256
#define ROWB 1664            // bytes per packed igate row (6*256 used + 128 pad)
#define CHPR 104             // 16B chunks per row
#define CHTOT (16 * CHPR)    // 1664 chunks per staging buffer

typedef __bf16 bf16x8 __attribute__((ext_vector_type(8)));
typedef float  f32x4  __attribute__((ext_vector_type(4)));
typedef int    i32x4  __attribute__((ext_vector_type(4)));

__device__ __bf16 g_wih[768 * 256];
__device__ __bf16 g_whh[768 * 256];
__device__ __bf16 g_xbf[TT * 256];
__device__ __align__(64) unsigned char g_ig[(size_t)TT * ROWB];

__device__ __forceinline__ void gl_lds16(const void* g, void* l) {
  __builtin_amdgcn_global_load_lds(
      (const __attribute__((address_space(1))) void*)(unsigned long long)(uintptr_t)g,
      (__attribute__((address_space(3))) void*)(unsigned int)(uintptr_t)l,
      16, 0, 0);
}

__device__ __forceinline__ bf16x8 as_bf16x8(i32x4 v) {
  bf16x8 r; __builtin_memcpy(&r, &v, 16); return r;
}
__device__ __forceinline__ float bfbits(uint32_t u) {
  float f; __builtin_memcpy(&f, &u, 4); return f;
}

__global__ void prep_w(const float* __restrict__ wih, const float* __restrict__ whh) {
  const int n = 768 * 256;
  for (int i = blockIdx.x * blockDim.x + threadIdx.x; i < n; i += gridDim.x * blockDim.x) {
    g_wih[i] = (__bf16)wih[i];
    g_whh[i] = (__bf16)whh[i];
  }
}

__global__ void prep_x(const float* __restrict__ x) {
  int i = (blockIdx.x * 256 + threadIdx.x) * 8;
  float4 a0 = *(const float4*)(x + i);
  float4 a1 = *(const float4*)(x + i + 4);
  bf16x8 v;
  v[0] = (__bf16)a0.x; v[1] = (__bf16)a0.y; v[2] = (__bf16)a0.z; v[3] = (__bf16)a0.w;
  v[4] = (__bf16)a1.x; v[5] = (__bf16)a1.y; v[6] = (__bf16)a1.z; v[7] = (__bf16)a1.w;
  *(bf16x8*)(g_xbf + i) = v;
}

// phase 1: igates = x @ W_ih^T + bias -> packed rows, fully coalesced writes.
__global__ __launch_bounds__(256) void gemm_ig(const float* __restrict__ bias) {
  __shared__ __align__(16) __bf16 a_s[128 * 64];
  __shared__ __align__(16) __bf16 b_s[128 * 64];
  const int tid = threadIdx.x;
  const int w = tid >> 6, lane = tid & 63, l15 = lane & 15, q = lane >> 4;
  const int mt = blockIdx.x / 6, ntb = blockIdx.x - mt * 6;
  const int m0 = mt * 128, n0 = ntb * 128;
  const int wm = w >> 1, wn = w & 1;

  f32x4 acc[4][4];
#pragma unroll
  for (int a = 0; a < 4; ++a)
#pragma unroll
    for (int b = 0; b < 4; ++b) acc[a][b] = (f32x4){0.f, 0.f, 0.f, 0.f};

  for (int kc = 0; kc < 4; ++kc) {
#pragma unroll
    for (int i = 0; i < 4; ++i) {
      int pslot = i * 256 + tid;
      int row = pslot >> 3, cb = (pslot & 7) ^ (row & 7);
      gl_lds16((const char*)g_xbf + ((size_t)(m0 + row) * 256 + kc * 64) * 2 + cb * 16,
               (char*)a_s + (i * 256 + (tid & ~63)) * 16);
      gl_lds16((const char*)g_wih + ((size_t)(n0 + row) * 256 + kc * 64) * 2 + cb * 16,
               (char*)b_s + (i * 256 + (tid & ~63)) * 16);
    }
    __syncthreads();
#pragma unroll
    for (int ks = 0; ks < 2; ++ks) {
      bf16x8 af[4], bfr[4];
#pragma unroll
      for (int tm = 0; tm < 4; ++tm) {
        int row = wm * 64 + tm * 16 + l15;
        int cb = (ks * 4 + q) ^ (row & 7);
        af[tm] = *(const bf16x8*)((const char*)a_s + row * 128 + cb * 16);
      }
#pragma unroll
      for (int tn = 0; tn < 4; ++tn) {
        int row = wn * 64 + tn * 16 + l15;
        int cb = (ks * 4 + q) ^ (row & 7);
        bfr[tn] = *(const bf16x8*)((const char*)b_s + row * 128 + cb * 16);
      }
#pragma unroll
      for (int tm = 0; tm < 4; ++tm)
#pragma unroll
        for (int tn = 0; tn < 4; ++tn)
          acc[tm][tn] = __builtin_amdgcn_mfma_f32_16x16x32_bf16(af[tm], bfr[tn], acc[tm][tn], 0, 0, 0);
    }
    __syncthreads();
  }
  float bv[4];
#pragma unroll
  for (int tn = 0; tn < 4; ++tn) bv[tn] = bias[n0 + wn * 64 + tn * 16 + l15];
#pragma unroll
  for (int tm = 0; tm < 4; ++tm) {
#pragma unroll
    for (int tp = 0; tp < 2; ++tp) {
#pragma unroll
      for (int r = 0; r < 4; ++r) {
        int t = m0 + wm * 64 + tm * 16 + q * 4 + r;
        __bf16 lo = (__bf16)(acc[tm][tp * 2][r] + bv[tp * 2]);
        __bf16 hi = (__bf16)(acc[tm][tp * 2 + 1][r] + bv[tp * 2 + 1]);
        unsigned short ulo, uhi;
        __builtin_memcpy(&ulo, &lo, 2); __builtin_memcpy(&uhi, &hi, 2);
        uint32_t u = (uint32_t)ulo | ((uint32_t)uhi << 16);
        *(uint32_t*)(g_ig + (size_t)t * ROWB + ntb * 256 + (wn * 2 + tp) * 64 + l15 * 4) = u;
      }
    }
  }
}

// phase 2: the scan. W_hh pinned in AGPRs ("a" constraint: 192 AGPR + <=64 arch
// fits the unified 256/wave budget at waves_per_eu(2,2); MFMA B reads AGPR
// directly on gfx950). Previous build spilled these 192 regs to scratch
// (VGPR_Count=128) and reloaded ~49KB/wave/iter -> that was the bottleneck.
__global__ __launch_bounds__(512)
__attribute__((amdgpu_waves_per_eu(2, 2)))
void gru_scan(const float* __restrict__ state, const int* __restrict__ start,
              const float* __restrict__ bias_n, float* __restrict__ out) {
  __shared__ __align__(16) __bf16 h_s[16][264];
  __shared__ __align__(16) unsigned char ig_s[2][16 * ROWB];
  __shared__ int flg_s[16 * 132];
  __shared__ int s_arr[17];

  const int tid = threadIdx.x;
  const int w = tid >> 6, lane = tid & 63, l15 = lane & 15, q = lane >> 4;
  const int jrow0 = w * 32 + l15;

  if (tid < 17) {
    int t = (blockIdx.x * NCH + tid) * CNOM;
    if (t > 0) { while (t < TT && start[t] == 0) t++; }
    s_arr[tid] = t;
  }
  for (int i = tid; i < 16 * 264; i += 512) (&h_s[0][0])[i] = (__bf16)0.f;
  __syncthreads();

  int sa[4], len[4];
#pragma unroll
  for (int r = 0; r < 4; ++r) {
    sa[r] = s_arr[q * 4 + r];
    len[r] = s_arr[q * 4 + r + 1] - sa[r];
  }
  int ML = 0;
  for (int m = 0; m < 16; ++m) { int L = s_arr[m + 1] - s_arr[m]; ML = L > ML ? L : ML; }
  ML = __builtin_amdgcn_readfirstlane(ML);  // uniform: keep loop bound in SGPR

  // start-flag table: flg_s[m][kk] = start[s_arr[m]+kk] for kk<128
  for (int idx = tid; idx < 2048; idx += 512) {
    int m = idx >> 7, kk = idx & 127;
    int t = s_arr[m] + kk;
    flg_s[m * 132 + kk] = (t < TT) ? start[t] : 0;
  }

  // staging geometry: chunk c = it*512+tid -> (row, 16B offset)
  int srow[4], goff[4];
#pragma unroll
  for (int it = 0; it < 4; ++it) {
    int c = it * 512 + tid;
    int cc = c < CHTOT ? c : 0;
    int row = cc / CHPR;
    srow[it] = s_arr[row];
    goff[it] = (cc - row * CHPR) * 16;
  }

  const int start0 = start[0];
  if (blockIdx.x == 0 && tid < 256) h_s[0][tid] = start0 ? (__bf16)0.f : (__bf16)state[tid];

  // stage igates for k=0 into buf 0
#pragma unroll
  for (int it = 0; it < 4; ++it) {
    if (it < 3 || tid < CHTOT - 1536) {
      int t = srow[it]; t = t > TT - 1 ? TT - 1 : t;
      gl_lds16(g_ig + (size_t)t * ROWB + goff[it],
               (char*)&ig_s[0][0] + (it * 512 + (tid & ~63)) * 16);
    }
  }

  // W_hh fragments, pinned in AGPRs
  i32x4 whh_i[2][3][8];
#pragma unroll
  for (int p = 0; p < 2; ++p)
#pragma unroll
    for (int c = 0; c < 3; ++c) {
      const __bf16* rp = &g_whh[(c * 256 + w * 32 + p * 16 + l15) * 256 + q * 8];
#pragma unroll
      for (int ks = 0; ks < 8; ++ks) whh_i[p][c][ks] = *(const i32x4*)(rp + ks * 32);
    }
#pragma unroll
  for (int p = 0; p < 2; ++p)
#pragma unroll
    for (int c = 0; c < 3; ++c)
#pragma unroll
      for (int ks = 0; ks < 8; ++ks) asm volatile("" : "+a"(whh_i[p][c][ks]));

  const float bn2[2] = { bias_n[jrow0], bias_n[jrow0 + 16] };

  float hreg[2][4];
#pragma unroll
  for (int p = 0; p < 2; ++p)
#pragma unroll
    for (int r = 0; r < 4; ++r) hreg[p][r] = 0.f;
  if (blockIdx.x == 0 && q == 0 && !start0) {
    hreg[0][0] = state[jrow0];
    hreg[1][0] = state[jrow0 + 16];
  }
  const int cw = (w >> 2) * 256 + ((w & 3) * 16 + l15) * 4;  // lane const: seg sub-offset
  __syncthreads();

  for (int k = 0; k < ML; ++k) {
    const int bc = k & 1;
    // async prefetch igates(k+1) into the other buffer
#pragma unroll
    for (int it = 0; it < 4; ++it) {
      if (it < 3 || tid < CHTOT - 1536) {
        int t = srow[it] + k + 1; t = t > TT - 1 ? TT - 1 : t;
        gl_lds16(g_ig + (size_t)t * ROWB + goff[it],
                 (char*)&ig_s[bc ^ 1][0] + (it * 512 + (tid & ~63)) * 16);
      }
    }

    f32x4 acc[2][3];
#pragma unroll
    for (int p = 0; p < 2; ++p)
#pragma unroll
      for (int c = 0; c < 3; ++c) acc[p][c] = (f32x4){0.f, 0.f, 0.f, 0.f};
#pragma unroll
    for (int ks = 0; ks < 8; ++ks) {
      bf16x8 hf = *(const bf16x8*)&h_s[l15][ks * 32 + q * 8];
#pragma unroll
      for (int p = 0; p < 2; ++p)
#pragma unroll
        for (int c = 0; c < 3; ++c)
          acc[p][c] = __builtin_amdgcn_mfma_f32_16x16x32_bf16(
              hf, as_bf16x8(whh_i[p][c][ks]), acc[p][c], 0, 0, 0);
    }

    // fnext computed after the MFMA block: shorter live range across 48 MFMAs
    int fnext[4];
    if (k + 1 < 128) {
#pragma unroll
      for (int r = 0; r < 4; ++r) fnext[r] = flg_s[(q * 4 + r) * 132 + k + 1];
    } else {
#pragma unroll
      for (int r = 0; r < 4; ++r) {
        int t = sa[r] + k + 1; t = t > TT - 1 ? TT - 1 : t;
        fnext[r] = start[t];
      }
    }

    const unsigned char* igB = &ig_s[bc][0];
#pragma unroll
    for (int r = 0; r < 4; ++r) {
      int m = q * 4 + r;
      const unsigned char* bp = igB + m * ROWB + cw;
      uint32_t vr = *(const uint32_t*)(bp);
      uint32_t vz = *(const uint32_t*)(bp + 512);
      uint32_t vn = *(const uint32_t*)(bp + 1024);
#pragma unroll
      for (int p = 0; p < 2; ++p) {
        float igr = bfbits(p ? (vr & 0xffff0000u) : (vr << 16));
        float igz = bfbits(p ? (vz & 0xffff0000u) : (vz << 16));
        float ign = bfbits(p ? (vn & 0xffff0000u) : (vn << 16));
        float rp = acc[p][0][r] + igr;
        float zp = acc[p][1][r] + igz;
        float hv = acc[p][2][r] + bn2[p];
        float rg = 1.f / (1.f + __expf(-rp));
        float zg = 1.f / (1.f + __expf(-zp));
        float np = ign + rg * hv;
        np = fminf(fmaxf(np, -30.f), 30.f);
        float e2 = __expf(2.f * np);
        float ng = (e2 - 1.f) / (e2 + 1.f);
        float hn = ng + zg * (hreg[p][r] - ng);
        if (k < len[r]) out[(size_t)(sa[r] + k) * 256 + jrow0 + p * 16] = hn;
        hreg[p][r] = fnext[r] ? 0.f : hn;
      }
    }
    __syncthreads();   // h_s/ig_s[bc] reads done; prefetched buffer complete
#pragma unroll
    for (int p = 0; p < 2; ++p)
#pragma unroll
      for (int r = 0; r < 4; ++r)
        h_s[q * 4 + r][jrow0 + p * 16] = (__bf16)hreg[p][r];
    __syncthreads();   // h_s visible for next step
  }
}

__global__ void fin_copy(float* __restrict__ out) {
  int i = threadIdx.x;
  out[(size_t)TT * 256 + i] = out[((size_t)TT - 1) * 256 + i];
}

extern "C" void kernel_launch(void* const* d_in, const int* in_sizes, int n_in,
                              void* d_out, int out_size, void* d_ws, size_t ws_size,
                              hipStream_t stream) {
  const float* x      = (const float*)d_in[0];
  const float* state  = (const float*)d_in[1];
  const int*   start  = (const int*)d_in[2];
  const float* wih    = (const float*)d_in[4];
  const float* whh    = (const float*)d_in[5];
  const float* bias   = (const float*)d_in[6];
  const float* bias_n = (const float*)d_in[7];
  float* out = (float*)d_out;

  prep_w<<<256, 256, 0, stream>>>(wih, whh);
  prep_x<<<8192, 256, 0, stream>>>(x);
  gemm_ig<<<3072, 256, 0, stream>>>(bias);
  gru_scan<<<NBLK, 512, 0, stream>>>(state, start, bias_n, out);
  fin_copy<<<1, 256, 0, stream>>>(out);
}

// Round 2
// 293.061 us; speedup vs baseline: 1.2790x; 1.2790x over previous
//
#include <hip/hip_runtime.h>
#include <hip/hip_bf16.h>
#include <stdint.h>

#define TT   65536
#define NCH  16
#define CNOM 16
#define NBLK 256
#define ROWB 1664            // bytes per packed igate row (6*256 used + 128 pad)

typedef __bf16 bf16x8 __attribute__((ext_vector_type(8)));
typedef float  f32x4  __attribute__((ext_vector_type(4)));
typedef int    i32x4  __attribute__((ext_vector_type(4)));

__device__ __bf16 g_wih[768 * 256];
__device__ __bf16 g_whh[768 * 256];
__device__ __bf16 g_xbf[TT * 256];
__device__ __align__(64) unsigned char g_ig[(size_t)TT * ROWB];

__device__ __forceinline__ void gl_lds16(const void* g, void* l) {
  __builtin_amdgcn_global_load_lds(
      (const __attribute__((address_space(1))) void*)(unsigned long long)(uintptr_t)g,
      (__attribute__((address_space(3))) void*)(unsigned int)(uintptr_t)l,
      16, 0, 0);
}

__device__ __forceinline__ bf16x8 as_bf16x8(i32x4 v) {
  bf16x8 r; __builtin_memcpy(&r, &v, 16); return r;
}
__device__ __forceinline__ float bfbits(uint32_t u) {
  float f; __builtin_memcpy(&f, &u, 4); return f;
}

__global__ void prep_w(const float* __restrict__ wih, const float* __restrict__ whh) {
  const int n = 768 * 256;
  for (int i = blockIdx.x * blockDim.x + threadIdx.x; i < n; i += gridDim.x * blockDim.x) {
    g_wih[i] = (__bf16)wih[i];
    g_whh[i] = (__bf16)whh[i];
  }
}

__global__ void prep_x(const float* __restrict__ x) {
  int i = (blockIdx.x * 256 + threadIdx.x) * 8;
  float4 a0 = *(const float4*)(x + i);
  float4 a1 = *(const float4*)(x + i + 4);
  bf16x8 v;
  v[0] = (__bf16)a0.x; v[1] = (__bf16)a0.y; v[2] = (__bf16)a0.z; v[3] = (__bf16)a0.w;
  v[4] = (__bf16)a1.x; v[5] = (__bf16)a1.y; v[6] = (__bf16)a1.z; v[7] = (__bf16)a1.w;
  *(bf16x8*)(g_xbf + i) = v;
}

// phase 1: igates = x @ W_ih^T + bias -> packed rows, fully coalesced writes.
__global__ __launch_bounds__(256) void gemm_ig(const float* __restrict__ bias) {
  __shared__ __align__(16) __bf16 a_s[128 * 64];
  __shared__ __align__(16) __bf16 b_s[128 * 64];
  const int tid = threadIdx.x;
  const int w = tid >> 6, lane = tid & 63, l15 = lane & 15, q = lane >> 4;
  const int mt = blockIdx.x / 6, ntb = blockIdx.x - mt * 6;
  const int m0 = mt * 128, n0 = ntb * 128;
  const int wm = w >> 1, wn = w & 1;

  f32x4 acc[4][4];
#pragma unroll
  for (int a = 0; a < 4; ++a)
#pragma unroll
    for (int b = 0; b < 4; ++b) acc[a][b] = (f32x4){0.f, 0.f, 0.f, 0.f};

  for (int kc = 0; kc < 4; ++kc) {
#pragma unroll
    for (int i = 0; i < 4; ++i) {
      int pslot = i * 256 + tid;
      int row = pslot >> 3, cb = (pslot & 7) ^ (row & 7);
      gl_lds16((const char*)g_xbf + ((size_t)(m0 + row) * 256 + kc * 64) * 2 + cb * 16,
               (char*)a_s + (i * 256 + (tid & ~63)) * 16);
      gl_lds16((const char*)g_wih + ((size_t)(n0 + row) * 256 + kc * 64) * 2 + cb * 16,
               (char*)b_s + (i * 256 + (tid & ~63)) * 16);
    }
    __syncthreads();
#pragma unroll
    for (int ks = 0; ks < 2; ++ks) {
      bf16x8 af[4], bfr[4];
#pragma unroll
      for (int tm = 0; tm < 4; ++tm) {
        int row = wm * 64 + tm * 16 + l15;
        int cb = (ks * 4 + q) ^ (row & 7);
        af[tm] = *(const bf16x8*)((const char*)a_s + row * 128 + cb * 16);
      }
#pragma unroll
      for (int tn = 0; tn < 4; ++tn) {
        int row = wn * 64 + tn * 16 + l15;
        int cb = (ks * 4 + q) ^ (row & 7);
        bfr[tn] = *(const bf16x8*)((const char*)b_s + row * 128 + cb * 16);
      }
#pragma unroll
      for (int tm = 0; tm < 4; ++tm)
#pragma unroll
        for (int tn = 0; tn < 4; ++tn)
          acc[tm][tn] = __builtin_amdgcn_mfma_f32_16x16x32_bf16(af[tm], bfr[tn], acc[tm][tn], 0, 0, 0);
    }
    __syncthreads();
  }
  float bv[4];
#pragma unroll
  for (int tn = 0; tn < 4; ++tn) bv[tn] = bias[n0 + wn * 64 + tn * 16 + l15];
#pragma unroll
  for (int tm = 0; tm < 4; ++tm) {
#pragma unroll
    for (int tp = 0; tp < 2; ++tp) {
#pragma unroll
      for (int r = 0; r < 4; ++r) {
        int t = m0 + wm * 64 + tm * 16 + q * 4 + r;
        __bf16 lo = (__bf16)(acc[tm][tp * 2][r] + bv[tp * 2]);
        __bf16 hi = (__bf16)(acc[tm][tp * 2 + 1][r] + bv[tp * 2 + 1]);
        unsigned short ulo, uhi;
        __builtin_memcpy(&ulo, &lo, 2); __builtin_memcpy(&uhi, &hi, 2);
        uint32_t u = (uint32_t)ulo | ((uint32_t)uhi << 16);
        *(uint32_t*)(g_ig + (size_t)t * ROWB + ntb * 256 + (wn * 2 + tp) * 64 + l15 * 4) = u;
      }
    }
  }
}

// phase 2: the scan, restructured.
//  - igates: direct per-thread global loads (no LDS staging, no barrier dep),
//    register double-buffered, prefetched 1 iter ahead.
//  - h_s double-buffered -> ONE raw barrier/iter (lgkmcnt(0) only; vmcnt
//    never drained in the loop).
//  - W_hh: r-gate (c=0) fragments live in per-wave LDS [w][f][lane] (128 KB,
//    lane-contiguous => conflict-free, f*1024 fits ds offset imm);
//    z/n gates (c=1,2) in 128 VGPRs. ~220 live regs < 256 => no spill.
__global__ __launch_bounds__(512)
__attribute__((amdgpu_waves_per_eu(2, 2)))
void gru_scan(const float* __restrict__ state, const int* __restrict__ start,
              const float* __restrict__ bias_n, float* __restrict__ out) {
  __shared__ __align__(16) __bf16 h_s[2][16][264];
  __shared__ __align__(16) unsigned char whh_lds[8 * 16 * 1024];
  __shared__ int flg_s[16 * 132];
  __shared__ int s_arr[17];

  const int tid = threadIdx.x;
  const int w = tid >> 6, lane = tid & 63, l15 = lane & 15, q = lane >> 4;
  const int jrow0 = w * 32 + l15;

  if (tid < 17) {
    int t = (blockIdx.x * NCH + tid) * CNOM;
    if (t > 0) { while (t < TT && start[t] == 0) t++; }
    s_arr[tid] = t;
  }
  for (int i = tid; i < 16 * 264; i += 512) (&h_s[0][0][0])[i] = (__bf16)0.f;
  __syncthreads();

  int sa[4], len[4];
#pragma unroll
  for (int r = 0; r < 4; ++r) {
    sa[r] = s_arr[q * 4 + r];
    len[r] = s_arr[q * 4 + r + 1] - sa[r];
  }
  int ML = 0;
  for (int m = 0; m < 16; ++m) { int L = s_arr[m + 1] - s_arr[m]; ML = L > ML ? L : ML; }
  ML = __builtin_amdgcn_readfirstlane(ML);

  // start-flag table: flg_s[m][kk] = start[s_arr[m]+kk] for kk<128
  for (int idx = tid; idx < 2048; idx += 512) {
    int m = idx >> 7, kk = idx & 127;
    int t = s_arr[m] + kk;
    flg_s[m * 132 + kk] = (t < TT) ? start[t] : 0;
  }

  // W_hh c=0 (r-gate) -> per-wave LDS; c=1,2 -> registers
  char* lp = (char*)whh_lds + w * 16384 + lane * 16;
#pragma unroll
  for (int p = 0; p < 2; ++p)
#pragma unroll
    for (int ks = 0; ks < 8; ++ks) {
      i32x4 t = *(const i32x4*)&g_whh[(size_t)(w * 32 + p * 16 + l15) * 256 + q * 8 + ks * 32];
      *(i32x4*)(lp + (p * 8 + ks) * 1024) = t;
    }
  i32x4 whh_r[2][2][8];
#pragma unroll
  for (int p = 0; p < 2; ++p)
#pragma unroll
    for (int c = 1; c < 3; ++c)
#pragma unroll
      for (int ks = 0; ks < 8; ++ks)
        whh_r[p][c - 1][ks] =
            *(const i32x4*)&g_whh[(size_t)(c * 256 + w * 32 + p * 16 + l15) * 256 + q * 8 + ks * 32];

  const float bn2[2] = { bias_n[jrow0], bias_n[jrow0 + 16] };

  const int start0 = start[0];
  if (blockIdx.x == 0 && tid < 256) h_s[0][0][tid] = start0 ? (__bf16)0.f : (__bf16)state[tid];

  float hreg[2][4];
#pragma unroll
  for (int p = 0; p < 2; ++p)
#pragma unroll
    for (int r = 0; r < 4; ++r) hreg[p][r] = 0.f;
  if (blockIdx.x == 0 && q == 0 && !start0) {
    hreg[0][0] = state[jrow0];
    hreg[1][0] = state[jrow0 + 16];
  }

  // igate direct-load geometry
  const int cw = (w >> 2) * 256 + ((w & 3) * 16 + l15) * 4;
  const uint32_t offlim = (uint32_t)(TT - 1) * ROWB + (uint32_t)cw;
  uint32_t off[4];
#pragma unroll
  for (int r = 0; r < 4; ++r) off[r] = (uint32_t)sa[r] * ROWB + (uint32_t)cw;

  const unsigned char* gig = g_ig;
  uint32_t igA[12], igB[12];
#pragma unroll
  for (int r = 0; r < 4; ++r) {
    igA[r * 3 + 0] = *(const uint32_t*)(gig + off[r]);
    igA[r * 3 + 1] = *(const uint32_t*)(gig + off[r] + 512);
    igA[r * 3 + 2] = *(const uint32_t*)(gig + off[r] + 1024);
    uint32_t nx = off[r] + ROWB; off[r] = nx > offlim ? offlim : nx;
  }
  __syncthreads();

  auto step = [&](int k, uint32_t (&cur)[12], uint32_t (&nxt)[12]) {
    // prefetch igates(k+1) -> regs (latency hidden under MFMA + next barrier)
#pragma unroll
    for (int r = 0; r < 4; ++r) {
      nxt[r * 3 + 0] = *(const uint32_t*)(gig + off[r]);
      nxt[r * 3 + 1] = *(const uint32_t*)(gig + off[r] + 512);
      nxt[r * 3 + 2] = *(const uint32_t*)(gig + off[r] + 1024);
      uint32_t nx = off[r] + ROWB; off[r] = nx > offlim ? offlim : nx;
    }
    int fnext[4];
    if (k + 1 < 128) {
#pragma unroll
      for (int r = 0; r < 4; ++r) fnext[r] = flg_s[(q * 4 + r) * 132 + k + 1];
    } else {
#pragma unroll
      for (int r = 0; r < 4; ++r) {
        int t = sa[r] + k + 1; t = t > TT - 1 ? TT - 1 : t;
        fnext[r] = start[t];
      }
    }

    const __bf16* hb = &h_s[k & 1][0][0] + l15 * 264 + q * 8;
#pragma unroll
    for (int p = 0; p < 2; ++p) {
      f32x4 a0 = (f32x4){0.f, 0.f, 0.f, 0.f};
      f32x4 a1 = (f32x4){0.f, 0.f, 0.f, 0.f};
      f32x4 a2 = (f32x4){0.f, 0.f, 0.f, 0.f};
#pragma unroll
      for (int ks = 0; ks < 8; ++ks) {
        bf16x8 hf = *(const bf16x8*)(hb + ks * 32);
        i32x4 b0 = *(const i32x4*)(lp + (p * 8 + ks) * 1024);
        a0 = __builtin_amdgcn_mfma_f32_16x16x32_bf16(hf, as_bf16x8(b0), a0, 0, 0, 0);
        a1 = __builtin_amdgcn_mfma_f32_16x16x32_bf16(hf, as_bf16x8(whh_r[p][0][ks]), a1, 0, 0, 0);
        a2 = __builtin_amdgcn_mfma_f32_16x16x32_bf16(hf, as_bf16x8(whh_r[p][1][ks]), a2, 0, 0, 0);
      }
#pragma unroll
      for (int r = 0; r < 4; ++r) {
        uint32_t vr = cur[r * 3 + 0];
        uint32_t vz = cur[r * 3 + 1];
        uint32_t vn = cur[r * 3 + 2];
        float igr = bfbits(p ? (vr & 0xffff0000u) : (vr << 16));
        float igz = bfbits(p ? (vz & 0xffff0000u) : (vz << 16));
        float ign = bfbits(p ? (vn & 0xffff0000u) : (vn << 16));
        float rp_ = a0[r] + igr;
        float zp_ = a1[r] + igz;
        float hv  = a2[r] + bn2[p];
        float rg = 1.f / (1.f + __expf(-rp_));
        float zg = 1.f / (1.f + __expf(-zp_));
        float np = ign + rg * hv;
        np = fminf(fmaxf(np, -30.f), 30.f);
        float e2 = __expf(2.f * np);
        float ng = (e2 - 1.f) / (e2 + 1.f);
        float hn = ng + zg * (hreg[p][r] - ng);
        if (k < len[r]) out[(size_t)(sa[r] + k) * 256 + jrow0 + p * 16] = hn;
        hreg[p][r] = fnext[r] ? 0.f : hn;
      }
    }
    __bf16* hw = &h_s[(k + 1) & 1][0][0];
#pragma unroll
    for (int p = 0; p < 2; ++p)
#pragma unroll
      for (int r = 0; r < 4; ++r)
        hw[(q * 4 + r) * 264 + jrow0 + p * 16] = (__bf16)hreg[p][r];
    // one raw barrier per step: drain LDS only; vmcnt stays in flight
    asm volatile("s_waitcnt lgkmcnt(0)" ::: "memory");
    __builtin_amdgcn_s_barrier();
  };

  for (int k = 0; k < ML; ) {
    step(k, igA, igB); ++k;
    if (k < ML) { step(k, igB, igA); ++k; }
  }
}

__global__ void fin_copy(float* __restrict__ out) {
  int i = threadIdx.x;
  out[(size_t)TT * 256 + i] = out[((size_t)TT - 1) * 256 + i];
}

extern "C" void kernel_launch(void* const* d_in, const int* in_sizes, int n_in,
                              void* d_out, int out_size, void* d_ws, size_t ws_size,
                              hipStream_t stream) {
  const float* x      = (const float*)d_in[0];
  const float* state  = (const float*)d_in[1];
  const int*   start  = (const int*)d_in[2];
  const float* wih    = (const float*)d_in[4];
  const float* whh    = (const float*)d_in[5];
  const float* bias   = (const float*)d_in[6];
  const float* bias_n = (const float*)d_in[7];
  float* out = (float*)d_out;

  prep_w<<<256, 256, 0, stream>>>(wih, whh);
  prep_x<<<8192, 256, 0, stream>>>(x);
  gemm_ig<<<3072, 256, 0, stream>>>(bias);
  gru_scan<<<NBLK, 512, 0, stream>>>(state, start, bias_n, out);
  fin_copy<<<1, 256, 0, stream>>>(out);
}